// Round 2
// baseline (454.871 us; speedup 1.0000x reference)
//
#include <hip/hip_runtime.h>
#include <hip/hip_bf16.h>
#include <math.h>

// Sizes (fixed by the problem)
#define B 1024
#define L 20
#define D 50
#define AD 52          // D padded to multiple of 4 for float4
#define M_GAT 5120
#define S_GAT 10
#define ALPHA 0.9f
#define QSCALE 0.14142135623730951f  // 1/sqrt(50)

// ---------------------------------------------------------------------------
// Kernel 1: emb = item_emb[sess] + pop_emb[pop]; qkv projection.
// Writes emb (B*L*50) and Q/K/V transposed+padded: plane layout [3][L][B][AD],
// Q prescaled by 1/sqrt(D).
// ---------------------------------------------------------------------------
__global__ __launch_bounds__(64) void emb_qkv_kernel(
    const float* __restrict__ item_emb, const float* __restrict__ pop_emb,
    const int* __restrict__ input_session, const int* __restrict__ input_pop,
    const float* __restrict__ in_w, const float* __restrict__ in_b,
    float* __restrict__ emb_ws, float* __restrict__ qkvT)
{
    const int bl = blockIdx.x;            // 0 .. B*L-1
    const int s = bl / L, l = bl % L;
    const int lane = threadIdx.x;
    __shared__ float er[AD];
    const int is = input_session[bl];
    const int ip = input_pop[bl];
    if (lane < D) {
        float e = item_emb[(size_t)is * D + lane] + pop_emb[(size_t)ip * D + lane];
        er[lane] = e;
        emb_ws[(size_t)bl * D + lane] = e;
    } else if (lane < AD) {
        er[lane] = 0.f;
    }
    __syncthreads();
    const size_t plane = (size_t)L * B * AD;
    const size_t rowbase = ((size_t)l * B + s) * AD;
    // zero the 2 pad elements of each of the 3 planes
    if (lane < 6) {
        int which = lane >> 1, dd = D + (lane & 1);
        qkvT[which * plane + rowbase + dd] = 0.f;
    }
    for (int r = 0; r < 3; ++r) {
        int e = lane + 64 * r;
        if (e < 3 * D) {
            float a = in_b[e];
            #pragma unroll
            for (int d = 0; d < D; ++d) a += er[d] * in_w[e * D + d];
            int which = e / D, dd = e % D;
            if (which == 0) a *= QSCALE;
            qkvT[which * plane + rowbase + dd] = a;
        }
    }
}

// ---------------------------------------------------------------------------
// Kernel 2: DSP branch. low = F @ emb (per feature), y = (1-b^2) low + (1+b^2) emb,
// layernorm over D, store 0.9*dsp.
// ---------------------------------------------------------------------------
__global__ __launch_bounds__(256) void dsp_kernel(
    const float* __restrict__ emb_ws, const float* __restrict__ beta,
    const float* __restrict__ ln_w, const float* __restrict__ ln_b,
    float* __restrict__ dsp_ws)
{
    const int b = blockIdx.x;
    const int tid = threadIdx.x;
    __shared__ float se[L][D];
    __shared__ float sy[L][D];
    __shared__ float F[L][L];
    __shared__ float mu[L], rs[L];
    for (int i = tid; i < L * D; i += 256) se[i / D][i % D] = emb_ws[(size_t)b * L * D + i];
    // FIX: L*L = 400 > 256 threads — must stride this loop.
    for (int i = tid; i < L * L; i += 256) {
        int l = i / L, t = i % L;
        F[l][t] = (1.f + 2.f * cosf(6.283185307179586f * (float)(l - t) / (float)L)) * (1.f / (float)L);
    }
    __syncthreads();
    for (int i = tid; i < L * D; i += 256) {
        int l = i / D, d = i % D;
        float low = 0.f;
        #pragma unroll
        for (int t = 0; t < L; ++t) low += F[l][t] * se[t][d];
        float be = beta[d], b2 = be * be;
        sy[l][d] = (1.f - b2) * low + (1.f + b2) * se[l][d];
    }
    __syncthreads();
    if (tid < L) {
        float m = 0.f;
        for (int d = 0; d < D; ++d) m += sy[tid][d];
        m *= (1.f / (float)D);
        float v = 0.f;
        for (int d = 0; d < D; ++d) { float x = sy[tid][d] - m; v += x * x; }
        v *= (1.f / (float)D);
        mu[tid] = m; rs[tid] = rsqrtf(v + 1e-12f);
    }
    __syncthreads();
    for (int i = tid; i < L * D; i += 256) {
        int l = i / D, d = i % D;
        float val = ln_w[d] * (sy[l][d] - mu[l]) * rs[l] + ln_b[d];
        dsp_ws[(size_t)b * L * D + i] = ALPHA * val;
    }
}

// ---------------------------------------------------------------------------
// Kernel 3: batch-axis attention per l (flash-style, online softmax),
// then out-projection, writes hidden = 0.9*dsp + 0.1*attn.
// Grid: (B/64, L). Block 256 = 16 row-groups x 16 col-threads; 4x4 reg tiles.
// ---------------------------------------------------------------------------
#define TS 64
#define PTP 68   // pad for p-tile (keeps float4 alignment, 2-way banks only)

__global__ __launch_bounds__(256) void attn_kernel(
    const float* __restrict__ qkvT,
    const float* __restrict__ out_w, const float* __restrict__ out_b,
    const float* __restrict__ dsp_ws, float* __restrict__ out_hidden)
{
    const int l = blockIdx.y;
    const int s0 = blockIdx.x * TS;
    const int tid = threadIdx.x;
    const int g = tid >> 4;        // row group 0..15 -> rows si0..si0+3
    const int mcol = tid & 15;     // col thread
    const int si0 = g * 4;

    __shared__ float qs[TS][AD];
    __shared__ float kt[TS][AD];
    __shared__ float vt[TS][AD];
    __shared__ float pt[TS][PTP];

    const size_t plane = (size_t)L * B * AD;
    const float* Qg = qkvT + ((size_t)l * B + s0) * AD;
    const float* Kg = qkvT + plane + (size_t)l * B * AD;
    const float* Vg = qkvT + 2 * plane + (size_t)l * B * AD;

    {   // load Q tile (64 x 52 floats)
        const float4* src = (const float4*)Qg;
        float4* dst = (float4*)&qs[0][0];
        for (int i = tid; i < TS * AD / 4; i += 256) dst[i] = src[i];
    }

    float4 acc[4];
    float mrun[4], lrun[4];
    #pragma unroll
    for (int r = 0; r < 4; ++r) {
        acc[r] = make_float4(0.f, 0.f, 0.f, 0.f);
        mrun[r] = -3.0e38f; lrun[r] = 0.f;
    }

    for (int tt = 0; tt < B / TS; ++tt) {
        __syncthreads();   // previous tile's pt/vt reads complete
        {
            const float4* ks = (const float4*)(Kg + (size_t)(tt * TS) * AD);
            const float4* vs = (const float4*)(Vg + (size_t)(tt * TS) * AD);
            float4* kd = (float4*)&kt[0][0];
            float4* vd = (float4*)&vt[0][0];
            for (int i = tid; i < TS * AD / 4; i += 256) { kd[i] = ks[i]; vd[i] = vs[i]; }
        }
        __syncthreads();

        // ---- S tile: rows si0+r, cols mcol+16c ----
        float sv[4][4];
        #pragma unroll
        for (int r = 0; r < 4; ++r)
            #pragma unroll
            for (int c = 0; c < 4; ++c) sv[r][c] = 0.f;

        #pragma unroll
        for (int dc = 0; dc < AD / 4; ++dc) {
            float4 q4[4], k4[4];
            #pragma unroll
            for (int r = 0; r < 4; ++r) q4[r] = *(const float4*)&qs[si0 + r][dc * 4];
            #pragma unroll
            for (int c = 0; c < 4; ++c) k4[c] = *(const float4*)&kt[mcol + 16 * c][dc * 4];
            #pragma unroll
            for (int r = 0; r < 4; ++r)
                #pragma unroll
                for (int c = 0; c < 4; ++c)
                    sv[r][c] += q4[r].x * k4[c].x + q4[r].y * k4[c].y
                              + q4[r].z * k4[c].z + q4[r].w * k4[c].w;
        }

        // ---- online softmax stats (16-lane row groups) ----
        #pragma unroll
        for (int r = 0; r < 4; ++r) {
            float tm = fmaxf(fmaxf(sv[r][0], sv[r][1]), fmaxf(sv[r][2], sv[r][3]));
            #pragma unroll
            for (int mask = 1; mask < 16; mask <<= 1) tm = fmaxf(tm, __shfl_xor(tm, mask));
            float nm = fmaxf(mrun[r], tm);
            float f = __expf(mrun[r] - nm);
            float p0 = __expf(sv[r][0] - nm);
            float p1 = __expf(sv[r][1] - nm);
            float p2 = __expf(sv[r][2] - nm);
            float p3 = __expf(sv[r][3] - nm);
            float ps = p0 + p1 + p2 + p3;
            #pragma unroll
            for (int mask = 1; mask < 16; mask <<= 1) ps += __shfl_xor(ps, mask);
            lrun[r] = lrun[r] * f + ps;
            mrun[r] = nm;
            acc[r].x *= f; acc[r].y *= f; acc[r].z *= f; acc[r].w *= f;
            pt[si0 + r][mcol]      = p0;
            pt[si0 + r][mcol + 16] = p1;
            pt[si0 + r][mcol + 32] = p2;
            pt[si0 + r][mcol + 48] = p3;
        }
        __syncthreads();

        // ---- PV: acc[r] covers d = mcol*4 .. mcol*4+3 (mcol<13) ----
        if (mcol < 13) {
            const int d0 = mcol * 4;
            #pragma unroll
            for (int tc = 0; tc < TS / 4; ++tc) {
                float4 p4[4], v4[4];
                #pragma unroll
                for (int r = 0; r < 4; ++r) p4[r] = *(const float4*)&pt[si0 + r][tc * 4];
                #pragma unroll
                for (int c = 0; c < 4; ++c) v4[c] = *(const float4*)&vt[tc * 4 + c][d0];
                #pragma unroll
                for (int r = 0; r < 4; ++r) {
                    acc[r].x += p4[r].x * v4[0].x + p4[r].y * v4[1].x + p4[r].z * v4[2].x + p4[r].w * v4[3].x;
                    acc[r].y += p4[r].x * v4[0].y + p4[r].y * v4[1].y + p4[r].z * v4[2].y + p4[r].w * v4[3].y;
                    acc[r].z += p4[r].x * v4[0].z + p4[r].y * v4[1].z + p4[r].z * v4[2].z + p4[r].w * v4[3].z;
                    acc[r].w += p4[r].x * v4[0].w + p4[r].y * v4[1].w + p4[r].z * v4[2].w + p4[r].w * v4[3].w;
                }
            }
        }
    }
    __syncthreads();
    // normalized ctx -> qs (reuse)
    if (mcol < 13) {
        const int d0 = mcol * 4;
        #pragma unroll
        for (int r = 0; r < 4; ++r) {
            float inv = 1.f / lrun[r];
            float4 c4 = make_float4(acc[r].x * inv, acc[r].y * inv, acc[r].z * inv, acc[r].w * inv);
            *(float4*)&qs[si0 + r][d0] = c4;
        }
    }
    __syncthreads();
    // out projection + final blend
    if (mcol < 13) {
        const int e0 = mcol * 4;
        float4 o[4];
        #pragma unroll
        for (int r = 0; r < 4; ++r) o[r] = make_float4(0.f, 0.f, 0.f, 0.f);
        for (int dc = 0; dc < AD / 4; ++dc) {
            float w4[4][4];
            #pragma unroll
            for (int c = 0; c < 4; ++c) {
                int e = e0 + c;
                #pragma unroll
                for (int j = 0; j < 4; ++j) {
                    int dd = dc * 4 + j;
                    // FIX: per-element guard — no OOB read past out_w row/buffer.
                    w4[c][j] = (e < D && dd < D) ? out_w[e * D + dd] : 0.f;
                }
            }
            #pragma unroll
            for (int r = 0; r < 4; ++r) {
                float4 c4 = *(const float4*)&qs[si0 + r][dc * 4];
                o[r].x += c4.x * w4[0][0] + c4.y * w4[0][1] + c4.z * w4[0][2] + c4.w * w4[0][3];
                o[r].y += c4.x * w4[1][0] + c4.y * w4[1][1] + c4.z * w4[1][2] + c4.w * w4[1][3];
                o[r].z += c4.x * w4[2][0] + c4.y * w4[2][1] + c4.z * w4[2][2] + c4.w * w4[2][3];
                o[r].w += c4.x * w4[3][0] + c4.y * w4[3][1] + c4.z * w4[3][2] + c4.w * w4[3][3];
            }
        }
        #pragma unroll
        for (int r = 0; r < 4; ++r) {
            int s = s0 + si0 + r;
            size_t base = ((size_t)s * L + l) * D;
            float vals[4] = { o[r].x, o[r].y, o[r].z, o[r].w };
            #pragma unroll
            for (int c = 0; c < 4; ++c) {
                int e = e0 + c;
                if (e < D)
                    out_hidden[base + e] = dsp_ws[base + e] + (1.f - ALPHA) * (vals[c] + out_b[e]);
            }
        }
    }
}

// ---------------------------------------------------------------------------
// Kernel 4: GGNN, one block per batch element, everything in LDS.
// ---------------------------------------------------------------------------
__global__ __launch_bounds__(256) void ggnn_kernel(
    const float* __restrict__ item_emb, const int* __restrict__ node_items,
    const float* __restrict__ A,
    const float* __restrict__ w_in, const float* __restrict__ b_in,
    const float* __restrict__ w_out, const float* __restrict__ b_out,
    const float* __restrict__ w_rzh, const float* __restrict__ b_rzh,
    const float* __restrict__ w_rz_old, const float* __restrict__ b_rz_old,
    const float* __restrict__ w_h_old, const float* __restrict__ b_h_old,
    float* __restrict__ out_ggnn)
{
    const int b = blockIdx.x, tid = threadIdx.x;
    __shared__ float h[L][D];
    __shared__ float Ab[L][2 * L];
    __shared__ float ain[L][D], aout[L][D];
    __shared__ float hinp[L][2 * D];
    __shared__ float rzh[L][3 * D];
    __shared__ float rzo[L][2 * D];
    __shared__ float rh[L][D];

    for (int i = tid; i < L * 2 * L; i += 256) Ab[i / (2 * L)][i % (2 * L)] = A[(size_t)b * L * 2 * L + i];
    for (int i = tid; i < L * D; i += 256) {
        int n = i / D, d = i % D;
        h[n][d] = item_emb[(size_t)node_items[b * L + n] * D + d];
    }
    __syncthreads();
    for (int i = tid; i < L * D; i += 256) {
        int n = i / D, d = i % D;
        float s1 = 0.f, s2 = 0.f;
        #pragma unroll
        for (int m = 0; m < L; ++m) { s1 += Ab[n][m] * h[m][d]; s2 += Ab[n][L + m] * h[m][d]; }
        ain[n][d] = s1; aout[n][d] = s2;
    }
    __syncthreads();
    for (int i = tid; i < L * 2 * D; i += 256) {
        int n = i / (2 * D), e = i % (2 * D);
        float s;
        if (e < D) {
            s = b_in[e];
            for (int d = 0; d < D; ++d) s += ain[n][d] * w_in[e * D + d];
        } else {
            int e2 = e - D;
            s = b_out[e2];
            for (int d = 0; d < D; ++d) s += aout[n][d] * w_out[e2 * D + d];
        }
        hinp[n][e] = s;
    }
    __syncthreads();
    for (int i = tid; i < L * 3 * D; i += 256) {
        int n = i / (3 * D), e = i % (3 * D);
        float s = b_rzh[e];
        for (int j = 0; j < 2 * D; ++j) s += hinp[n][j] * w_rzh[e * 2 * D + j];
        rzh[n][e] = s;
    }
    for (int i = tid; i < L * 2 * D; i += 256) {
        int n = i / (2 * D), e = i % (2 * D);
        float s = b_rz_old[e];
        for (int d = 0; d < D; ++d) s += h[n][d] * w_rz_old[e * D + d];
        rzo[n][e] = s;
    }
    __syncthreads();
    for (int i = tid; i < L * D; i += 256) {
        int n = i / D, d = i % D;
        float r = 1.f / (1.f + __expf(-(rzo[n][d] + rzh[n][d])));
        rh[n][d] = r * h[n][d];
    }
    __syncthreads();
    for (int i = tid; i < L * D; i += 256) {
        int n = i / D, e = i % D;
        float s = b_h_old[e];
        for (int d = 0; d < D; ++d) s += rh[n][d] * w_h_old[e * D + d];
        float z = 1.f / (1.f + __expf(-(rzo[n][D + e] + rzh[n][D + e])));
        float hn = tanhf(rzh[n][2 * D + e] + s);
        out_ggnn[(size_t)b * L * D + i] = (1.f - z) * h[n][e] + z * hn;
    }
}

// ---------------------------------------------------------------------------
// Kernel 5: GAT, one 64-thread block per m.
// ---------------------------------------------------------------------------
__global__ __launch_bounds__(64) void gat_kernel(
    const float* __restrict__ self_vecs, const float* __restrict__ neigh_vecs,
    const float* __restrict__ gat_w, const float* __restrict__ gat_b,
    float* __restrict__ out_gat)
{
    const int m = blockIdx.x, lane = threadIdx.x;
    __shared__ float nsv[S_GAT + 1][D];
    __shared__ float sc[S_GAT + 1];
    __shared__ float ctx[D];
    if (lane < D) {
        float s_v = self_vecs[(size_t)m * D + lane];
        nsv[S_GAT][lane] = s_v;
        for (int s = 0; s < S_GAT; ++s)
            nsv[s][lane] = neigh_vecs[((size_t)m * S_GAT + s) * D + lane];
    }
    __syncthreads();
    if (lane < S_GAT + 1) {
        float s = 0.f;
        for (int d = 0; d < D; ++d) s += nsv[S_GAT][d] * nsv[lane][d];
        sc[lane] = s;
    }
    __syncthreads();
    if (lane == 0) {
        float mx = sc[0];
        for (int s = 1; s < S_GAT + 1; ++s) mx = fmaxf(mx, sc[s]);
        float sm = 0.f;
        for (int s = 0; s < S_GAT + 1; ++s) { float e = __expf(sc[s] - mx); sc[s] = e; sm += e; }
        float inv = 1.f / sm;
        for (int s = 0; s < S_GAT + 1; ++s) sc[s] *= inv;
    }
    __syncthreads();
    if (lane < D) {
        float c = 0.f;
        for (int s = 0; s < S_GAT + 1; ++s) c += sc[s] * nsv[s][lane];
        ctx[lane] = c;
    }
    __syncthreads();
    if (lane < D) {
        float o = gat_b[lane];
        for (int d = 0; d < D; ++d) o += ctx[d] * gat_w[lane * D + d];
        out_gat[(size_t)m * D + lane] = fmaxf(o, 0.f);
    }
}

// ---------------------------------------------------------------------------
extern "C" void kernel_launch(void* const* d_in, const int* in_sizes, int n_in,
                              void* d_out, int out_size, void* d_ws, size_t ws_size,
                              hipStream_t stream)
{
    const float* item_emb   = (const float*)d_in[0];
    const float* pop_emb    = (const float*)d_in[1];
    const float* beta       = (const float*)d_in[2];
    const float* ln_w       = (const float*)d_in[3];
    const float* ln_b       = (const float*)d_in[4];
    const float* in_proj_w  = (const float*)d_in[5];
    const float* in_proj_b  = (const float*)d_in[6];
    const float* out_proj_w = (const float*)d_in[7];
    const float* out_proj_b = (const float*)d_in[8];
    const float* w_in       = (const float*)d_in[9];
    const float* b_in       = (const float*)d_in[10];
    const float* w_out      = (const float*)d_in[11];
    const float* b_out      = (const float*)d_in[12];
    const float* w_rzh      = (const float*)d_in[13];
    const float* b_rzh      = (const float*)d_in[14];
    const float* w_rz_old   = (const float*)d_in[15];
    const float* b_rz_old   = (const float*)d_in[16];
    const float* w_h_old    = (const float*)d_in[17];
    const float* b_h_old    = (const float*)d_in[18];
    const float* gat_w      = (const float*)d_in[19];
    const float* gat_b      = (const float*)d_in[20];
    const float* A          = (const float*)d_in[21];
    const float* self_vecs  = (const float*)d_in[22];
    const float* neigh_vecs = (const float*)d_in[23];
    const int* input_session = (const int*)d_in[24];
    const int* input_pop     = (const int*)d_in[25];
    const int* node_items    = (const int*)d_in[26];

    float* ws = (float*)d_ws;
    float* emb_ws = ws;                         // B*L*D   = 1,024,000 f
    float* dsp_ws = ws + (size_t)B * L * D;     // 1,024,000 f
    float* qkvT   = ws + (size_t)2 * B * L * D; // 3*L*B*AD = 3,194,880 f  (~21 MB total)

    float* out_hidden = (float*)d_out;
    float* out_ggnn   = out_hidden + (size_t)B * L * D;
    float* out_gat    = out_hidden + (size_t)2 * B * L * D;

    emb_qkv_kernel<<<B * L, 64, 0, stream>>>(item_emb, pop_emb, input_session, input_pop,
                                             in_proj_w, in_proj_b, emb_ws, qkvT);
    dsp_kernel<<<B, 256, 0, stream>>>(emb_ws, beta, ln_w, ln_b, dsp_ws);
    attn_kernel<<<dim3(B / TS, L), 256, 0, stream>>>(qkvT, out_proj_w, out_proj_b,
                                                     dsp_ws, out_hidden);
    ggnn_kernel<<<B, 256, 0, stream>>>(item_emb, node_items, A,
                                       w_in, b_in, w_out, b_out,
                                       w_rzh, b_rzh, w_rz_old, b_rz_old,
                                       w_h_old, b_h_old, out_ggnn);
    gat_kernel<<<M_GAT, 64, 0, stream>>>(self_vecs, neigh_vecs, gat_w, gat_b, out_gat);
}